// Round 10
// baseline (135.934 us; speedup 1.0000x reference)
//
#include <hip/hip_runtime.h>

namespace {

constexpr int   kT = 512, kC = 512, kL = 128, kBlank = 511;
constexpr int   kCH   = 16;         // rows per chunk
constexpr int   kNCH  = kT / kCH;   // 32 chunks
constexpr int   kRing = 4;          // chunk ring depth
constexpr float kEps = 1e-7f, kLn2 = 0.6931471805599453f;

typedef float __attribute__((address_space(1))) f32g;
typedef float __attribute__((address_space(3))) f32l;

// Coalesced width-16 global->LDS: 64 lanes x 16B = 1KB (half a row).
__device__ __forceinline__ void glds16(const float* g, float* l) {
    __builtin_amdgcn_global_load_lds((const f32g*)g, (f32l*)l, 16, 0, 0);
}
__device__ __forceinline__ float rlane(float x, int l) {
    return __int_as_float(__builtin_amdgcn_readlane(__float_as_int(x), l));
}
__device__ __forceinline__ float bperm(int a, float x) {
    return __int_as_float(__builtin_amdgcn_ds_bpermute(a, __float_as_int(x)));
}
__device__ __forceinline__ float LOG2(float x) { return __builtin_amdgcn_logf(x); }

// Raw barrier: no compiler-inserted vmcnt(0) drain (unlike __syncthreads).
// Memory-clobber fences pin LDS/global ops on both sides (rule #18).
__device__ __forceinline__ void barrier_raw() {
    asm volatile("" ::: "memory");
    __builtin_amdgcn_s_barrier();
    asm volatile("" ::: "memory");
}

__global__ __launch_bounds__(192, 1) void ctc_fwd_kernel(
        const int* __restrict__ labels,
        const float* __restrict__ y_pred,
        float* __restrict__ out) {
    __shared__ __align__(16) float buf[kRing][kCH][kC];   // 128 KiB chunk ring

    const int tid  = (int)threadIdx.x;
    const int lane = tid & 63;
    const int wv   = tid >> 6;     // 0 = consumer, 1..2 = producers
    const int b    = (int)blockIdx.x;
    const float* yp  = y_pred + (size_t)b * kT * kC;
    const int*   lab = labels + b * kL;

    // ---- consumer-only constants (keep producer vmcnt stream pure) ----
    int  cls[4] = {kBlank, kBlank, kBlank, kBlank};
    bool skp[4] = {false, false, false, false};
    if (wv == 0) {
#pragma unroll
        for (int k = 0; k < 4; ++k) {
            const int s = lane + 64 * k;
            if (s & 1) {
                cls[k] = lab[(s - 1) >> 1];
                skp[k] = (s >= 3) && (lab[(s - 1) >> 1] != lab[(s - 3) >> 1]);
            }
        }
    }
    const int addr1 = (lane - 1) << 2;   // bpermute byte addrs (r2..r9-proven)
    const int addr2 = (lane - 2) << 2;

    // ---- prologue: producers stage chunks 0..2 (16 loads per wave each) ----
    if (wv >= 1) {
        const int r0 = (wv - 1) * 8;     // this wave's 8 rows of each chunk
        for (int ch = 0; ch < kRing - 1; ++ch) {
            for (int r = 0; r < 8; ++r) {
                const float* row = yp + (size_t)(ch * kCH + r0 + r) * kC;
                glds16(row + lane * 4,       &buf[ch][r0 + r][0]);
                glds16(row + 256 + lane * 4, &buf[ch][r0 + r][256]);
            }
        }
        // 48 in flight; wait until chunk 0's 16 landed (32 remain: chunks 1,2)
        asm volatile("s_waitcnt vmcnt(32)" ::: "memory");
    }
    barrier_raw();

    // ---- linear-domain scaled forward state ----
    float a[4] = {0.f, 0.f, 0.f, 0.f}, a256 = 0.f, etot = 0.f;

    for (int c = 0; c < kNCH; ++c) {
        if (wv >= 1) {
            // ---- producers: stage chunk c+3 (clamped tail keeps 16 loads per
            //      iteration -> vmcnt accounting uniform; clamped re-issues hit
            //      slots that are either dead or rewritten with identical data)
            const int pc = (c + 3 < kNCH) ? c + 3 : kNCH - 1;
            const int r0 = (wv - 1) * 8;
            float (*bf)[kC] = buf[(c + 3) & (kRing - 1)];
            for (int r = 0; r < 8; ++r) {
                const float* row = yp + (size_t)(pc * kCH + r0 + r) * kC;
                glds16(row + lane * 4,       &bf[r0 + r][0]);
                glds16(row + 256 + lane * 4, &bf[r0 + r][256]);
            }
            // outstanding <= 48 (chunks c+1..c+3); wait -> chunk c+1 resident.
            // NEVER 0: chunks c+2,c+3 stay in flight across the barrier (T4).
            asm volatile("s_waitcnt vmcnt(32)" ::: "memory");
        } else {
            // ---- consumer: 16 recurrence steps from chunk c (r9 body) ----
            float (*bf)[kC] = buf[c & (kRing - 1)];
            int rs = 0;
            if (c == 0) {
                float p0 = bf[0][cls[0]] + kEps;   // lane0 blank, lane1 label0
                a[0] = (lane < 2) ? p0 : 0.f;
                rs = 1;
            }
            float raw[4];
#pragma unroll
            for (int k = 0; k < 4; ++k) raw[k] = bf[rs][cls[k]];
            for (int r = rs; r < kCH; ++r) {
                float nraw[4] = {raw[0], raw[1], raw[2], raw[3]};
                if (r + 1 < kCH) {
#pragma unroll
                    for (int k = 0; k < 4; ++k) nraw[k] = bf[r + 1][cls[k]];
                }
                float p[4];
#pragma unroll
                for (int k = 0; k < 4; ++k) p[k] = raw[k] + kEps;
                float an[4];
#pragma unroll
                for (int k = 0; k < 4; ++k) {
                    const float s1 = bperm(addr1, a[k]);
                    const float s2 = bperm(addr2, a[k]);
                    float am1, am2;
                    if (k == 0) {
                        am1 = (lane == 0) ? 0.f : s1;
                        am2 = (lane <= 1) ? 0.f : s2;
                    } else {
                        const float e63 = rlane(a[k - 1], 63);
                        const float e62 = rlane(a[k - 1], 62);
                        am1 = (lane == 0) ? e63 : s1;
                        am2 = (lane == 0) ? e62 : ((lane == 1) ? e63 : s2);
                    }
                    const float a3v = skp[k] ? am2 : 0.f;
                    an[k] = (a[k] + am1 + a3v) * p[k];
                }
                {   // state 256 (blank tail, scalar)
                    const float a255 = rlane(a[3], 63);
                    const float pb   = rlane(p[0], 0);
                    a256 = (a256 + a255) * pb;
                }
#pragma unroll
                for (int k = 0; k < 4; ++k) { a[k] = an[k]; raw[k] = nraw[k]; }
            }
            // ---- lossless power-of-2 renorm every 2 chunks (32 steps) ----
            if (c & 1) {
                float m = fmaxf(fmaxf(a[0], a[1]), fmaxf(a[2], a[3]));
#pragma unroll
                for (int i = 1; i < 64; i <<= 1) m = fmaxf(m, __shfl_xor(m, i));
                m = fmaxf(m, a256);
                const int ex = (__float_as_int(m) >> 23) & 0xFF;
                if (ex > 1) {
                    const float sc = __int_as_float((254 - ex) << 23); // 2^(127-ex)
                    a[0] *= sc; a[1] *= sc; a[2] *= sc; a[3] *= sc; a256 *= sc;
                    etot += (float)(ex - 127);
                }
            }
        }
        barrier_raw();
    }

    // ---- loss = -ln2 * (log2(alpha255 + alpha256) + etot) ----
    if (wv == 0) {
        const float a255 = rlane(a[3], 63);
        const float s    = a255 + a256;
        const float loss = -kLn2 * (LOG2(s) + etot);
        if (lane == 0) out[b] = loss;
    }
}

} // namespace

extern "C" void kernel_launch(void* const* d_in, const int* in_sizes, int n_in,
                              void* d_out, int out_size, void* d_ws, size_t ws_size,
                              hipStream_t stream) {
    const int*   labels = (const int*)d_in[0];   // y_true [256,128] int32
    const float* y_pred = (const float*)d_in[1]; // y_pred [256,512,512] f32
    float*       out    = (float*)d_out;         // loss [256,1] f32
    (void)in_sizes; (void)n_in; (void)d_ws; (void)ws_size;
    hipLaunchKernelGGL(ctc_fwd_kernel, dim3(out_size), dim3(192), 0, stream,
                       labels, y_pred, out);
}

// Round 11
// 67.893 us; speedup vs baseline: 2.0022x; 2.0022x over previous
//
#include <hip/hip_runtime.h>

namespace {

constexpr int   kT = 512, kC = 512, kL = 128, kBlank = 511;
constexpr int   kCH  = 16;         // rows per chunk
constexpr int   kNCH = kT / kCH;   // 32 chunks
constexpr float kEps = 1e-7f, kLn2 = 0.6931471805599453f;

typedef float __attribute__((address_space(1))) f32g;
typedef float __attribute__((address_space(3))) f32l;

// Coalesced width-16 global->LDS: 64 lanes x 16B = 1KB (half a row).
__device__ __forceinline__ void glds16(const float* g, float* l) {
    __builtin_amdgcn_global_load_lds((const f32g*)g, (f32l*)l, 16, 0, 0);
}
__device__ __forceinline__ float rlane(float x, int l) {
    return __int_as_float(__builtin_amdgcn_readlane(__float_as_int(x), l));
}
__device__ __forceinline__ float bperm(int a, float x) {
    return __int_as_float(__builtin_amdgcn_ds_bpermute(a, __float_as_int(x)));
}
__device__ __forceinline__ float LOG2(float x) { return __builtin_amdgcn_logf(x); }

__global__ __launch_bounds__(128, 1) void ctc_fwd_kernel(
        const int* __restrict__ labels,
        const float* __restrict__ y_pred,
        float* __restrict__ out) {
    __shared__ __align__(16) float buf[2][kCH][kC];   // 64 KiB double buffer

    const int tid  = (int)threadIdx.x;
    const int lane = tid & 63;
    const int wv   = tid >> 6;           // 0 = consumer, 1 = producer
    const int b    = (int)blockIdx.x;
    const float* yp  = y_pred + (size_t)b * kT * kC;
    const int*   lab = labels + b * kL;

    // ---- consumer constants: state s = 4*lane + k (k=0..3), + scalar 256 ----
    // k even -> blank (no skip). k=1: cls lab[2l], skip vs lab[2l-1] (s>=3 <=> l>=1).
    // k=3: cls lab[2l+1], skip vs lab[2l].
    int   cls1 = kBlank, cls3 = kBlank;
    float skp1 = 0.f, skp3 = 0.f;
    if (wv == 0) {
        cls1 = lab[2 * lane];
        cls3 = lab[2 * lane + 1];
        skp1 = (lane >= 1 && lab[2 * lane] != lab[2 * lane - 1]) ? 1.f : 0.f;
        skp3 = (lab[2 * lane + 1] != lab[2 * lane]) ? 1.f : 0.f;
    }
    const int addr1 = (lane - 1) << 2;   // bpermute: lane i <- lane i-1

    // ---- prologue: producer stages chunk 0 (r9-proven path) ----
    if (wv == 1) {
        for (int r = 0; r < kCH; ++r) {
            const float* row = yp + (size_t)r * kC;
            glds16(row + lane * 4,       &buf[0][r][0]);
            glds16(row + 256 + lane * 4, &buf[0][r][256]);
        }
    }
    __syncthreads();

    // ---- linear-domain scaled forward state ----
    float a0 = 0.f, a1 = 0.f, a2 = 0.f, a3 = 0.f, a256 = 0.f, etot = 0.f;

    for (int c = 0; c < kNCH; ++c) {
        if (wv == 1) {
            // ---- producer: stage chunk c+1 (unchanged from r9) ----
            if (c + 1 < kNCH) {
                float (*bf)[kC] = buf[(c + 1) & 1];
                for (int r = 0; r < kCH; ++r) {
                    const float* row = yp + (size_t)((c + 1) * kCH + r) * kC;
                    glds16(row + lane * 4,       &bf[r][0]);
                    glds16(row + 256 + lane * 4, &bf[r][256]);
                }
            }
        } else {
            // ---- consumer: 16 recurrence steps; 1 bpermute per step ----
            float (*bf)[kC] = buf[c & 1];
            int rs = 0;
            if (c == 0) {
                const float pb0 = bf[0][kBlank] + kEps;
                const float pl0 = bf[0][cls1] + kEps;   // lane0: lab[0]
                a0 = (lane == 0) ? pb0 : 0.f;           // state 0
                a1 = (lane == 0) ? pl0 : 0.f;           // state 1
                rs = 1;
            }
            float rb = bf[rs][kBlank];   // same-address broadcast (blank)
            float r1 = bf[rs][cls1];
            float r3 = bf[rs][cls3];
            for (int r = rs; r < kCH; ++r) {
                float nb = rb, n1 = r1, n3 = r3;
                if (r + 1 < kCH) {       // prefetch next row's probs
                    nb = bf[r + 1][kBlank];
                    n1 = bf[r + 1][cls1];
                    n3 = bf[r + 1][cls3];
                }
                const float pb = rb + kEps;   // blank prob (k=0 and k=2)
                const float p1 = r1 + kEps;
                const float p3 = r3 + kEps;
                float sh3 = bperm(addr1, a3);          // prev-lane a3 (state 4l-1)
                sh3 = (lane == 0) ? 0.f : sh3;
                const float a255 = rlane(a3, 63);      // state 255 (pre-update)
                const float b0 = (a0 + sh3) * pb;                // s=4l (blank)
                const float b1 = (a1 + a0 + skp1 * sh3) * p1;    // s=4l+1
                const float b2 = (a2 + a1) * pb;                 // s=4l+2 (blank)
                const float b3 = (a3 + a2 + skp3 * a1) * p3;     // s=4l+3
                a256 = (a256 + a255) * pb;                       // s=256 (blank)
                a0 = b0; a1 = b1; a2 = b2; a3 = b3;
                rb = nb; r1 = n1; r3 = n3;
            }
            // ---- lossless power-of-2 renorm every 2 chunks (32 steps) ----
            if (c & 1) {
                float m = fmaxf(fmaxf(a0, a1), fmaxf(a2, a3));
#pragma unroll
                for (int i = 1; i < 64; i <<= 1) m = fmaxf(m, __shfl_xor(m, i));
                m = fmaxf(m, a256);
                const int ex = (__float_as_int(m) >> 23) & 0xFF;
                if (ex > 1) {
                    const float sc = __int_as_float((254 - ex) << 23); // 2^(127-ex)
                    a0 *= sc; a1 *= sc; a2 *= sc; a3 *= sc; a256 *= sc;
                    etot += (float)(ex - 127);
                }
            }
        }
        __syncthreads();
    }

    // ---- loss = -ln2 * (log2(alpha255 + alpha256) + etot) ----
    if (wv == 0) {
        const float a255 = rlane(a3, 63);   // state 255 = lane 63, k=3
        const float s    = a255 + a256;
        const float loss = -kLn2 * (LOG2(s) + etot);
        if (lane == 0) out[b] = loss;
    }
}

} // namespace

extern "C" void kernel_launch(void* const* d_in, const int* in_sizes, int n_in,
                              void* d_out, int out_size, void* d_ws, size_t ws_size,
                              hipStream_t stream) {
    const int*   labels = (const int*)d_in[0];   // y_true [256,128] int32
    const float* y_pred = (const float*)d_in[1]; // y_pred [256,512,512] f32
    float*       out    = (float*)d_out;         // loss [256,1] f32
    (void)in_sizes; (void)n_in; (void)d_ws; (void)ws_size;
    hipLaunchKernelGGL(ctc_fwd_kernel, dim3(out_size), dim3(128), 0, stream,
                       labels, y_pred, out);
}